// Round 6
// baseline (971.475 us; speedup 1.0000x reference)
//
#include <hip/hip_runtime.h>
#include <hip/hip_bf16.h>

typedef __attribute__((ext_vector_type(8))) short bf16x8;
typedef __attribute__((ext_vector_type(4))) float f32x4;

static __device__ __forceinline__ unsigned short f2bf(float x) {
    __hip_bfloat16 h = __float2bfloat16(x);
    return *(unsigned short*)&h;
}
static __device__ __forceinline__ float bflo(unsigned int w) { return __uint_as_float(w << 16); }
static __device__ __forceinline__ float bfhi(unsigned int w) { return __uint_as_float(w & 0xffff0000u); }
static __device__ __forceinline__ float bf1(unsigned short u) { return __uint_as_float(((unsigned int)u) << 16); }

// async global->LDS DMA, 16B per lane, dest = wave-uniform base + lane*16
typedef __attribute__((address_space(1))) const void gvoid;
typedef __attribute__((address_space(3))) void lvoid;
static __device__ __forceinline__ void gl_lds16(const void* g, void* l) {
    __builtin_amdgcn_global_load_lds((gvoid*)g, (lvoid*)l, 16, 0, 0);
}

#define PART_FLOATS 4718592   // 512*9216

// ---------------- conv1 + ReLU: [512,1,28,28] -> h1n NHWC bf16 [512,20,20,256] ----------
__global__ __launch_bounds__(320) void conv1_k(const float* __restrict__ in,
                                               const float* __restrict__ w,
                                               const float* __restrict__ bias,
                                               unsigned short* __restrict__ h1n) {
    int blk = blockIdx.x;
    int b = blk >> 4;
    int c0 = (blk & 15) * 16;
    __shared__ float img[784];
    __shared__ float wl[16 * 81];
    __shared__ float bl[16];
    __shared__ unsigned short tr[20 * 328];
    int tid = threadIdx.x;
    for (int t = tid; t < 784; t += 320) img[t] = in[b * 784 + t];
    for (int t = tid; t < 1296; t += 320) wl[t] = w[c0 * 81 + t];
    if (tid < 16) bl[tid] = bias[c0 + tid];
    __syncthreads();

    int co = tid / 20, oy = tid % 20;
    float wr[81];
#pragma unroll
    for (int k = 0; k < 81; k++) wr[k] = wl[co * 81 + k];
    float acc[20];
    float bv = bl[co];
#pragma unroll
    for (int ox = 0; ox < 20; ox++) acc[ox] = bv;

#pragma unroll
    for (int ky = 0; ky < 9; ky++) {
        const float* rp = &img[(oy + ky) * 28];
        float r[28];
#pragma unroll
        for (int v = 0; v < 7; v++) {
            float4 t4 = ((const float4*)rp)[v];
            r[v * 4 + 0] = t4.x; r[v * 4 + 1] = t4.y;
            r[v * 4 + 2] = t4.z; r[v * 4 + 3] = t4.w;
        }
#pragma unroll
        for (int kx = 0; kx < 9; kx++) {
            float wv = wr[ky * 9 + kx];
#pragma unroll
            for (int ox = 0; ox < 20; ox++) acc[ox] += r[ox + kx] * wv;
        }
    }
#pragma unroll
    for (int ox = 0; ox < 20; ox++)
        tr[oy * 328 + ox * 16 + co] = f2bf(fmaxf(acc[ox], 0.f));
    __syncthreads();
    for (int g = tid; g < 800; g += 320) {
        int p = g >> 1, half = g & 1;
        uint4 v = *(uint4*)&tr[(p / 20) * 328 + (p % 20) * 16 + half * 8];
        *(uint4*)&h1n[(b * 400 + p) * 256 + c0 + half * 8] = v;
    }
}

// ---------------- W2 transpose (84 kk planes; 81..83 zeroed for uniform split-K 4) -------
__global__ __launch_bounds__(256) void wt2_k(const float* __restrict__ w2,
                                             unsigned short* __restrict__ Wt2) {
    int cout = blockIdx.x;
    int ci = threadIdx.x;
    const float* src = w2 + (cout * 256 + ci) * 81;
#pragma unroll 1
    for (int kk = 0; kk < 81; kk++)
        Wt2[kk * 65536 + cout * 256 + ci] = f2bf(src[kk]);
#pragma unroll
    for (int kk = 81; kk < 84; kk++)
        Wt2[kk * 65536 + cout * 256 + ci] = 0;
}

// ---------------- conv2 implicit GEMM, bf16 MFMA, 128x128, split-K 4 ---------------------
// R15: conv2 was LDS-READ-BW-bound (R12 counters: 64 KB LDS read/block-round x 2 blk/CU
// / 128 B/cyc = 1024 cyc vs 320 cyc MFMA -> 31% ceiling = measured 30% MfmaUtil).
// Fix: B operand bypasses LDS -- direct global->VGPR 16 B loads (Wt2 is 11 MB,
// L2/L3-resident, reused by all 144 m-blocks). Element mapping identical to the old
// swizzled-LDS path, so MFMA fragment layout is unchanged. B frags ping-pong in NAMED
// register sets rB0/rB1 (rule #20: no runtime-indexed ext_vector arrays), prefetched
// one round ahead; the per-round __syncthreads vmcnt-drain guarantees arrival.
// A staging unchanged (global_load_lds dbuf + XOR swizzle via pre-swizzled source).
// LDS 64 -> 32 KB; occupancy ~3 blk/CU. New LDS ceiling ~42-60% MfmaUtil.
__global__ __launch_bounds__(256) void conv2_k(const unsigned short* __restrict__ h1n,
                                               const unsigned short* __restrict__ Wt2,
                                               const float* __restrict__ bias,
                                               float* __restrict__ u,
                                               float* __restrict__ part1,
                                               float* __restrict__ part23) {
    __shared__ unsigned short sA[2][128 * 64];   // 2 x 16 KB, XOR-swizzled A double-buffer
    int tid = threadIdx.x;
    int m0 = blockIdx.x * 128;
    int n0 = blockIdx.y * 128;
    int slice = blockIdx.z;
    int ks = slice * 21;

    int wv = tid >> 6, lane = tid & 63;
    int wm = wv >> 1, wn = wv & 1;
    int lr = lane & 15, quad = lane >> 4;

    // A staging geometry (per wave): 4 instrs, 8 rows per instr, pre-swizzled source
    int lrow = lane >> 3, lslot = lane & 7;
    int kcoff = (lslot ^ lrow) * 8;           // pre-swizzled chunk offset (shorts)
    int aG[4];
#pragma unroll
    for (int t = 0; t < 4; t++) {
        int r = wv * 32 + t * 8 + lrow;       // sA row this lane feeds in instr t
        int R = m0 + r;
        int b = R / 36, m = R % 36;
        int oy = m / 6, ox = m % 6;
        aG[t] = b * 102400 + oy * 10240 + ox * 512 + kcoff;
    }

    // B per-lane global base offsets (shorts) for frag (s = k-half, j = 16-col group)
    int bL[2][4];
#pragma unroll
    for (int s = 0; s < 2; s++)
#pragma unroll
        for (int j = 0; j < 4; j++)
            bL[s][j] = (n0 + wn * 64 + j * 16 + lr) * 256 + (s * 4 + quad) * 8;

    f32x4 acc[4][4];
#pragma unroll
    for (int i = 0; i < 4; i++)
#pragma unroll
        for (int j = 0; j < 4; j++) acc[i][j] = (f32x4){0.f, 0.f, 0.f, 0.f};

    auto stageA = [&](int buf, int rr) {
        int kk = ks + (rr >> 2), cr = rr & 3;      // wave-uniform -> SALU
        int aoff = (kk / 9) * 5120 + (kk % 9) * 256 + cr * 64;
        unsigned short* dA = &sA[buf][wv * 2048];
#pragma unroll
        for (int t = 0; t < 4; t++)
            gl_lds16(h1n + aG[t] + aoff, dA + t * 512);
    };

    bf16x8 rB0[2][4], rB1[2][4];   // named ping-pong B fragment registers
    auto loadB = [&](bf16x8 (&rB)[2][4], int rr) {
        int kk = ks + (rr >> 2), cr = rr & 3;
        int boff = kk * 65536 + cr * 64;
#pragma unroll
        for (int s = 0; s < 2; s++)
#pragma unroll
            for (int j = 0; j < 4; j++)
                rB[s][j] = *(const bf16x8*)(Wt2 + boff + bL[s][j]);
    };

    auto compute = [&](const unsigned short* pA, bf16x8 (&rB)[2][4]) {
#pragma unroll
        for (int s = 0; s < 2; s++) {
            bf16x8 af[4];
#pragma unroll
            for (int i = 0; i < 4; i++) {
                int arow = wm * 64 + i * 16 + lr;
                af[i] = *(bf16x8*)&pA[arow * 64 + 8 * ((s * 4 + quad) ^ (lr & 7))];
            }
#pragma unroll
            for (int i = 0; i < 4; i++)
#pragma unroll
                for (int j = 0; j < 4; j++)
                    acc[i][j] = __builtin_amdgcn_mfma_f32_16x16x32_bf16(
                        af[i], rB[s][j], acc[i][j], 0, 0, 0);
        }
    };

    // prologue: round-0 operands
    loadB(rB0, 0);
    stageA(0, 0);
    __syncthreads();

#pragma unroll 1
    for (int it = 0; it < 42; it++) {
        int rr = it * 2;
        // even round rr: compute from {sA[0], rB0}; prefetch rr+1 into {sA[1], rB1}
        loadB(rB1, rr + 1);                 // rr+1 <= 83 always
        stageA(1, rr + 1);
        compute(&sA[0][0], rB0);
        __syncthreads();                    // drains prefetch; it had full compute to land
        // odd round rr+1: compute from {sA[1], rB1}; prefetch rr+2 into {sA[0], rB0}
        if (rr + 2 < 84) { loadB(rB0, rr + 2); stageA(0, rr + 2); }
        compute(&sA[1][0], rB1);
        __syncthreads();
    }

    // epilogue: C/D layout col=lane&15, row=quad*4+reg
    float* dst = (slice == 0) ? u : ((slice == 1) ? part1 : part23 + (size_t)(slice - 2) * PART_FLOATS);
#pragma unroll
    for (int j = 0; j < 4; j++) {
        int col = n0 + wn * 64 + j * 16 + lr;
        float bv = (slice == 0) ? bias[col] : 0.f;
#pragma unroll
        for (int i = 0; i < 4; i++) {
#pragma unroll
            for (int rg = 0; rg < 4; rg++) {
                int RR = m0 + wm * 64 + i * 16 + quad * 4 + rg;
                int bb = RR / 36, mm = RR % 36;
                int oyy = mm / 6, oxx = mm % 6;
                dst[bb * 9216 + oxx * 1536 + oyy * 256 + col] = acc[i][j][rg] + bv;
            }
        }
    }
}

// ---------------- fold split-K partials: u += p1 + p2 + p3 -------------------------------
__global__ __launch_bounds__(256) void add_k(float* __restrict__ u,
                                             const float* __restrict__ p1,
                                             const float* __restrict__ p23) {
    int n = (blockIdx.x * 256 + threadIdx.x) * 4;
    float4 a = *(float4*)&u[n];
    float4 x = *(const float4*)&p1[n];
    float4 y = *(const float4*)&p23[n];
    float4 z = *(const float4*)&p23[PART_FLOATS + n];
    a.x += x.x + y.x + z.x;
    a.y += x.y + y.y + z.y;
    a.z += x.z + y.z + z.z;
    a.w += x.w + y.w + z.w;
    *(float4*)&u[n] = a;
}

// ---------------- u_hat: u[b,i,p] x W[i,j,p,q] -> uhat bf16 [b][j][i*16+q] ---------------
// R14 (verified): [b][j][i16q] layout; for fixed (j,bb) the block stores 2 KB fully
// contiguous within one j-iteration; route_k reads 512 B contiguous per wave per j.
__global__ __launch_bounds__(256) void uhat_k(const float* __restrict__ u,
                                              const float* __restrict__ W,
                                              unsigned short* __restrict__ uhat) {
    int i0 = blockIdx.x * 64;
    int b0 = blockIdx.y * 8;
    __shared__ float ul[8 * 64 * 9];
    __shared__ float wl[64 * 129];
    int tid = threadIdx.x;

    for (int t = tid; t < 4096; t += 256) {
        int bb = t >> 9, r = t & 511;
        ul[bb * 576 + (r >> 3) * 9 + (r & 7)] = u[(b0 + bb) * 9216 + i0 * 8 + r];
    }

    int il = tid & 63, g = tid >> 6;
    for (int j = 0; j < 10; j++) {
        __syncthreads();
        for (int t = tid; t < 2048; t += 256) {
            int li = t >> 5, off = (t & 31) * 4;
            float4 v = *(const float4*)&W[(i0 + li) * 1280 + j * 128 + off];
            float* d = &wl[li * 129 + off];
            d[0] = v.x; d[1] = v.y; d[2] = v.z; d[3] = v.w;
        }
        __syncthreads();
#pragma unroll 1
        for (int bb = 0; bb < 8; bb++) {
            float ur[8];
#pragma unroll
            for (int p = 0; p < 8; p++) ur[p] = ul[bb * 576 + il * 9 + p];
            float a[4];
#pragma unroll
            for (int k = 0; k < 4; k++) {
                int q = g * 4 + k;
                float s = 0.f;
#pragma unroll
                for (int p = 0; p < 8; p++) s += ur[p] * wl[il * 129 + p * 16 + q];
                a[k] = s;
            }
            unsigned int lo = (unsigned int)f2bf(a[0]) | ((unsigned int)f2bf(a[1]) << 16);
            unsigned int hi = (unsigned int)f2bf(a[2]) | ((unsigned int)f2bf(a[3]) << 16);
            uint2 pk; pk.x = lo; pk.y = hi;
            *(uint2*)&uhat[((size_t)(b0 + bb) * 10 + j) * 18432 + (size_t)(i0 + il) * 16 + g * 4] = pk;
        }
    }
}

// ---------------- fused dynamic routing: one block per batch sample ----------------------
// R13 (verified): b_ij in LDS, s/v in LDS, zero global atomics, no inter-kernel drains.
// uhat[b] (360 KB, L2/L3-resident) streamed 3x. R14: [b][j][i16q] layout -> 512 B
// contiguous per wave per j.
__global__ __launch_bounds__(256) void route_k(const unsigned short* __restrict__ uhat,
                                               float* __restrict__ out) {
    int b = blockIdx.x;
    int tid = threadIdx.x;
    int w = tid >> 6, lane = tid & 63;
    int ig = lane >> 2, qh = lane & 3;
    __shared__ float b_sh[1152 * 10];   // 46 KB
    __shared__ float s_red[4 * 160];
    __shared__ float v_sh[160];
    __shared__ float sc_sh[10];
    const unsigned short* ub = uhat + (size_t)b * 184320;

    float v_ln[10][4];   // this lane's v[j*16 + qh*4 + k]

    // reduce sp -> s -> squash -> v_sh -> v_ln  (shared tail for every pass)
    auto finish = [&](float sp[10][4]) {
#pragma unroll
        for (int j = 0; j < 10; j++)
#pragma unroll
            for (int k = 0; k < 4; k++) {
                float t = sp[j][k];
                t += __shfl_xor(t, 4);
                t += __shfl_xor(t, 8);
                t += __shfl_xor(t, 16);
                t += __shfl_xor(t, 32);
                sp[j][k] = t;
            }
        if (ig == 0) {   // lanes 0..3 of each wave hold the wave totals
#pragma unroll
            for (int j = 0; j < 10; j++) {
                f32x4 v4 = {sp[j][0], sp[j][1], sp[j][2], sp[j][3]};
                *(f32x4*)&s_red[w * 160 + j * 16 + qh * 4] = v4;
            }
        }
        __syncthreads();
        if (tid < 160) {
            float s = s_red[tid] + s_red[160 + tid] + s_red[320 + tid] + s_red[480 + tid];
            s_red[tid] = s;
        }
        __syncthreads();
        if (tid < 10) {
            float sq = 0.f;
#pragma unroll
            for (int q = 0; q < 16; q++) { float x = s_red[tid * 16 + q]; sq += x * x; }
            float norm = sqrtf(sq + 1e-8f);
            sc_sh[tid] = (sq / (1.0f + sq)) / norm;
        }
        __syncthreads();
        if (tid < 160) v_sh[tid] = s_red[tid] * sc_sh[tid >> 4];
        __syncthreads();
#pragma unroll
        for (int j = 0; j < 10; j++) {
            f32x4 v4 = *(const f32x4*)&v_sh[j * 16 + qh * 4];
            v_ln[j][0] = v4[0]; v_ln[j][1] = v4[1]; v_ln[j][2] = v4[2]; v_ln[j][3] = v4[3];
        }
        __syncthreads();
    };

    // ---- pass 1: c = 0.1 uniform ----
    {
        float sp[10][4];
#pragma unroll
        for (int j = 0; j < 10; j++)
#pragma unroll
            for (int k = 0; k < 4; k++) sp[j][k] = 0.f;
#pragma unroll 2
        for (int r = 0; r < 18; r++) {
            int i = r * 64 + w * 16 + ig;
            const unsigned short* up = ub + (size_t)i * 16 + qh * 4;
            uint2 uh[10];
#pragma unroll
            for (int j = 0; j < 10; j++) uh[j] = *(const uint2*)(up + (size_t)j * 18432);
#pragma unroll
            for (int j = 0; j < 10; j++) {
                sp[j][0] += 0.1f * bflo(uh[j].x);
                sp[j][1] += 0.1f * bfhi(uh[j].x);
                sp[j][2] += 0.1f * bflo(uh[j].y);
                sp[j][3] += 0.1f * bfhi(uh[j].y);
            }
        }
        finish(sp);
    }

    // ---- passes 2,3: delta = uhat.v, b update, softmax, s-accumulate ----
#pragma unroll 1
    for (int pass = 0; pass < 2; pass++) {
        bool first = (pass == 0);    // pass2: b_prev = 0, write b_sh; pass3: read b_sh
        float sp[10][4];
#pragma unroll
        for (int j = 0; j < 10; j++)
#pragma unroll
            for (int k = 0; k < 4; k++) sp[j][k] = 0.f;
#pragma unroll 2
        for (int r = 0; r < 18; r++) {
            int i = r * 64 + w * 16 + ig;
            const unsigned short* up = ub + (size_t)i * 16 + qh * 4;
            uint2 uh[10];
#pragma unroll
            for (int j = 0; j < 10; j++) uh[j] = *(const uint2*)(up + (size_t)j * 18432);
            float d[10];
#pragma unroll
            for (int j = 0; j < 10; j++) {
                d[j] = bflo(uh[j].x) * v_ln[j][0] + bfhi(uh[j].x) * v_ln[j][1]
                     + bflo(uh[j].y) * v_ln[j][2] + bfhi(uh[j].y) * v_ln[j][3];
            }
#pragma unroll
            for (int j = 0; j < 10; j++) {
                d[j] += __shfl_xor(d[j], 1);
                d[j] += __shfl_xor(d[j], 2);
            }
            float bn[10];
            if (first) {
#pragma unroll
                for (int j = 0; j < 10; j++) bn[j] = d[j];
#pragma unroll
                for (int j = 0; j < 10; j++)
                    if (qh == (j & 3)) b_sh[i * 10 + j] = bn[j];
            } else {
#pragma unroll
                for (int j = 0; j < 10; j++) bn[j] = b_sh[i * 10 + j] + d[j];
            }
            float m = bn[0];
#pragma unroll
            for (int j = 1; j < 10; j++) m = fmaxf(m, bn[j]);
            float e[10], sum = 0.f;
#pragma unroll
            for (int j = 0; j < 10; j++) { e[j] = __expf(bn[j] - m); sum += e[j]; }
            float inv = 1.f / sum;
#pragma unroll
            for (int j = 0; j < 10; j++) {
                float c = e[j] * inv;
                sp[j][0] += c * bflo(uh[j].x);
                sp[j][1] += c * bfhi(uh[j].x);
                sp[j][2] += c * bflo(uh[j].y);
                sp[j][3] += c * bfhi(uh[j].y);
            }
        }
        finish(sp);
    }

    if (tid < 160) out[b * 160 + tid] = v_sh[tid];
}

extern "C" void kernel_launch(void* const* d_in, const int* in_sizes, int n_in,
                              void* d_out, int out_size, void* d_ws, size_t ws_size,
                              hipStream_t stream) {
    const float* input = (const float*)d_in[0];
    const float* c1w = (const float*)d_in[1];
    const float* c1b = (const float*)d_in[2];
    const float* c2w = (const float*)d_in[3];
    const float* c2b = (const float*)d_in[4];
    const float* capW = (const float*)d_in[5];
    float* out = (float*)d_out;

    // ws layout (bytes):
    //   [0)            u fp32 [512][9216]                      18,874,368
    //   [+19529728)    conv2 split-K part1                     18,874,368
    //   [+43122688)    region B: {Wt2 84 planes + h1n + part2,3} then uhat bf16 reuse
    const size_t U_OFF = 0;
    const size_t L_OFF = 19529728;
    const size_t B_OFF = 43122688;
    const size_t WT2_BYTES = (size_t)84 * 65536 * 2;       // 11,010,048
    const size_t H1N_BYTES = 104857600;
    const size_t PART_BYTES = (size_t)PART_FLOATS * 4;     // 18,874,368
    const size_t CONV_BYTES = WT2_BYTES + H1N_BYTES + 2 * PART_BYTES;  // 153.6 MB
    if (ws_size < B_OFF + CONV_BYTES) return;

    char* wsb = (char*)d_ws;
    float* u_buf = (float*)(wsb + U_OFF);
    float* part1  = (float*)(wsb + L_OFF);
    unsigned short* Wt2 = (unsigned short*)(wsb + B_OFF);
    unsigned short* h1n = (unsigned short*)(wsb + B_OFF + WT2_BYTES);
    float* part23 = (float*)(wsb + B_OFF + WT2_BYTES + H1N_BYTES);
    unsigned short* uhatb = (unsigned short*)(wsb + B_OFF);

    size_t availB = ws_size - B_OFF;
    int Cr = 0;
    const int cands[7] = {512, 256, 128, 64, 32, 16, 8};
    for (int k = 0; k < 7; k++) {
        if ((size_t)cands[k] * 368640 <= availB) { Cr = cands[k]; break; }
    }
    if (Cr == 0) return;

    wt2_k<<<256, 256, 0, stream>>>(c2w, Wt2);
    conv1_k<<<512 * 16, 320, 0, stream>>>(input, c1w, c1b, h1n);
    conv2_k<<<dim3(144, 2, 4), 256, 0, stream>>>(h1n, Wt2, c2b, u_buf, part1, part23);
    add_k<<<4608, 256, 0, stream>>>(u_buf, part1, part23);

    for (int b0 = 0; b0 < 512; b0 += Cr) {
        uhat_k<<<dim3(18, Cr / 8), 256, 0, stream>>>(u_buf + (size_t)b0 * 9216, capW,
                                                     uhatb + (size_t)b0 * 184320);
        route_k<<<Cr, 256, 0, stream>>>(uhatb + (size_t)b0 * 184320, out + (size_t)b0 * 160);
    }
}

// Round 7
// 743.470 us; speedup vs baseline: 1.3067x; 1.3067x over previous
//
#include <hip/hip_runtime.h>
#include <hip/hip_bf16.h>

typedef __attribute__((ext_vector_type(8))) short bf16x8;
typedef __attribute__((ext_vector_type(4))) float f32x4;

static __device__ __forceinline__ unsigned short f2bf(float x) {
    __hip_bfloat16 h = __float2bfloat16(x);
    return *(unsigned short*)&h;
}
static __device__ __forceinline__ float bflo(unsigned int w) { return __uint_as_float(w << 16); }
static __device__ __forceinline__ float bfhi(unsigned int w) { return __uint_as_float(w & 0xffff0000u); }
static __device__ __forceinline__ float bf1(unsigned short u) { return __uint_as_float(((unsigned int)u) << 16); }

// async global->LDS DMA, 16B per lane, dest = wave-uniform base + lane*16
typedef __attribute__((address_space(1))) const void gvoid;
typedef __attribute__((address_space(3))) void lvoid;
static __device__ __forceinline__ void gl_lds16(const void* g, void* l) {
    __builtin_amdgcn_global_load_lds((gvoid*)g, (lvoid*)l, 16, 0, 0);
}

#define PART_FLOATS 4718592   // 512*9216

// ---------------- conv1 + ReLU: [512,1,28,28] -> h1n NHWC bf16 [512,20,20,256] ----------
__global__ __launch_bounds__(320) void conv1_k(const float* __restrict__ in,
                                               const float* __restrict__ w,
                                               const float* __restrict__ bias,
                                               unsigned short* __restrict__ h1n) {
    int blk = blockIdx.x;
    int b = blk >> 4;
    int c0 = (blk & 15) * 16;
    __shared__ float img[784];
    __shared__ float wl[16 * 81];
    __shared__ float bl[16];
    __shared__ unsigned short tr[20 * 328];
    int tid = threadIdx.x;
    for (int t = tid; t < 784; t += 320) img[t] = in[b * 784 + t];
    for (int t = tid; t < 1296; t += 320) wl[t] = w[c0 * 81 + t];
    if (tid < 16) bl[tid] = bias[c0 + tid];
    __syncthreads();

    int co = tid / 20, oy = tid % 20;
    float wr[81];
#pragma unroll
    for (int k = 0; k < 81; k++) wr[k] = wl[co * 81 + k];
    float acc[20];
    float bv = bl[co];
#pragma unroll
    for (int ox = 0; ox < 20; ox++) acc[ox] = bv;

#pragma unroll
    for (int ky = 0; ky < 9; ky++) {
        const float* rp = &img[(oy + ky) * 28];
        float r[28];
#pragma unroll
        for (int v = 0; v < 7; v++) {
            float4 t4 = ((const float4*)rp)[v];
            r[v * 4 + 0] = t4.x; r[v * 4 + 1] = t4.y;
            r[v * 4 + 2] = t4.z; r[v * 4 + 3] = t4.w;
        }
#pragma unroll
        for (int kx = 0; kx < 9; kx++) {
            float wv = wr[ky * 9 + kx];
#pragma unroll
            for (int ox = 0; ox < 20; ox++) acc[ox] += r[ox + kx] * wv;
        }
    }
#pragma unroll
    for (int ox = 0; ox < 20; ox++)
        tr[oy * 328 + ox * 16 + co] = f2bf(fmaxf(acc[ox], 0.f));
    __syncthreads();
    for (int g = tid; g < 800; g += 320) {
        int p = g >> 1, half = g & 1;
        uint4 v = *(uint4*)&tr[(p / 20) * 328 + (p % 20) * 16 + half * 8];
        *(uint4*)&h1n[(b * 400 + p) * 256 + c0 + half * 8] = v;
    }
}

// ---------------- W2 transpose (84 kk planes; 81..83 zeroed for uniform split-K 4) -------
__global__ __launch_bounds__(256) void wt2_k(const float* __restrict__ w2,
                                             unsigned short* __restrict__ Wt2) {
    int cout = blockIdx.x;
    int ci = threadIdx.x;
    const float* src = w2 + (cout * 256 + ci) * 81;
#pragma unroll 1
    for (int kk = 0; kk < 81; kk++)
        Wt2[kk * 65536 + cout * 256 + ci] = f2bf(src[kk]);
#pragma unroll
    for (int kk = 81; kk < 84; kk++)
        Wt2[kk * 65536 + cout * 256 + ci] = 0;
}

// ---------------- conv2 implicit GEMM, bf16 MFMA, 128x128, split-K 4 ---------------------
// R17: R12 structure (2-phase dbuf global_load_lds prefetch, one barrier/round) with
// BK 64 -> 32. LDS 64 -> 32 KB => 5 blocks/CU (was 2): all 1152 blocks co-resident,
// zero tail sets, ~2.5x waves to hide the per-round drain latency (R12 counters were
// latency-bound: Mfma 30 / VALU 17 / HBM 18 / occ 18, all idle-ish; LDS-BW floor 135us).
// R16 (direct-B-register loads) REGRESSED 290->540us: 512B-strided 16-line gathers on
// the critical path; reverted.
// BK=32 swizzle (re-derived, both-sides): row = 32 shorts = 4 chunks of 16B. Store
// chunk c of row r from GLOBAL chunk c ^ ((r>>1)&3); read chunk quad ^ ((lr>>1)&3).
// 16 lanes hit slot-groups (lr&1)*4 + quad^((lr>>1)&3) = 8 groups x 2 = 2-way = free.
// grid (144, 2, 4) = 1152 blocks; slice kk planes [21s, 21s+21), 168 rounds each.
__global__ __launch_bounds__(256) void conv2_k(const unsigned short* __restrict__ h1n,
                                               const unsigned short* __restrict__ Wt2,
                                               const float* __restrict__ bias,
                                               float* __restrict__ u,
                                               float* __restrict__ part1,
                                               float* __restrict__ part23) {
    __shared__ unsigned short sA[2][128 * 32];   // 2 x 8 KB, XOR-swizzled A dbuf
    __shared__ unsigned short sB[2][128 * 32];   // 2 x 8 KB, XOR-swizzled B dbuf
    int tid = threadIdx.x;
    int m0 = blockIdx.x * 128;
    int n0 = blockIdx.y * 128;
    int slice = blockIdx.z;
    int ks = slice * 21;

    int wv = tid >> 6, lane = tid & 63;
    int wm = wv >> 1, wn = wv & 1;
    int lr = lane & 15, quad = lane >> 4;

    // staging geometry (per wave): 2 instrs for A + 2 for B, 16 rows per instr
    // instr t, lane l -> row_local = wv*32 + t*16 + (l>>2), chunk c = l&3,
    // fetch global chunk c ^ ((row_local>>1)&3)
    int aG[2], bG[2];
#pragma unroll
    for (int t = 0; t < 2; t++) {
        int rl = wv * 32 + t * 16 + (lane >> 2);
        int gch = (lane & 3) ^ ((rl >> 1) & 3);
        int R = m0 + rl;
        int b = R / 36, m = R % 36;
        int oy = m / 6, ox = m % 6;
        aG[t] = b * 102400 + oy * 10240 + ox * 512 + gch * 8;
        bG[t] = (n0 + rl) * 256 + gch * 8;
    }

    f32x4 acc[4][4];
#pragma unroll
    for (int i = 0; i < 4; i++)
#pragma unroll
        for (int j = 0; j < 4; j++) acc[i][j] = (f32x4){0.f, 0.f, 0.f, 0.f};

    auto stage = [&](int buf, int rr) {
        int kk = ks + (rr >> 3), cr8 = rr & 7;     // wave-uniform -> SALU
        int aoff = (kk / 9) * 5120 + (kk % 9) * 256 + cr8 * 32;
        int boff = kk * 65536 + cr8 * 32;
        unsigned short* dA = &sA[buf][wv * 1024];
        unsigned short* dB = &sB[buf][wv * 1024];
#pragma unroll
        for (int t = 0; t < 2; t++)
            gl_lds16(h1n + aG[t] + aoff, dA + t * 512);
#pragma unroll
        for (int t = 0; t < 2; t++)
            gl_lds16(Wt2 + bG[t] + boff, dB + t * 512);
    };

    int rch = 8 * (quad ^ ((lr >> 1) & 3));        // per-lane read chunk offset (shorts)

    auto compute = [&](const unsigned short* pA, const unsigned short* pB) {
        bf16x8 af[4], bf[4];
#pragma unroll
        for (int i = 0; i < 4; i++)
            af[i] = *(const bf16x8*)&pA[(wm * 64 + i * 16 + lr) * 32 + rch];
#pragma unroll
        for (int j = 0; j < 4; j++)
            bf[j] = *(const bf16x8*)&pB[(wn * 64 + j * 16 + lr) * 32 + rch];
#pragma unroll
        for (int i = 0; i < 4; i++)
#pragma unroll
            for (int j = 0; j < 4; j++)
                acc[i][j] = __builtin_amdgcn_mfma_f32_16x16x32_bf16(
                    af[i], bf[j], acc[i][j], 0, 0, 0);
    };

    // prologue: fill buf0, drain, barrier
    stage(0, 0);
    __syncthreads();

    int cur = 0;
#pragma unroll 1
    for (int rr = 0; rr < 168; rr++) {
        if (rr < 167) stage(cur ^ 1, rr + 1);   // prefetch next round (stays in flight)
        compute(&sA[cur][0], &sB[cur][0]);
        __syncthreads();   // drains prefetch vmcnt(0); it had the whole compute to land
        cur ^= 1;
    }

    // epilogue: C/D layout col=lane&15, row=quad*4+reg
    float* dst = (slice == 0) ? u : ((slice == 1) ? part1 : part23 + (size_t)(slice - 2) * PART_FLOATS);
#pragma unroll
    for (int j = 0; j < 4; j++) {
        int col = n0 + wn * 64 + j * 16 + lr;
        float bv = (slice == 0) ? bias[col] : 0.f;
#pragma unroll
        for (int i = 0; i < 4; i++) {
#pragma unroll
            for (int rg = 0; rg < 4; rg++) {
                int RR = m0 + wm * 64 + i * 16 + quad * 4 + rg;
                int bb = RR / 36, mm = RR % 36;
                int oyy = mm / 6, oxx = mm % 6;
                dst[bb * 9216 + oxx * 1536 + oyy * 256 + col] = acc[i][j][rg] + bv;
            }
        }
    }
}

// ---------------- fold split-K partials: u += p1 + p2 + p3 -------------------------------
__global__ __launch_bounds__(256) void add_k(float* __restrict__ u,
                                             const float* __restrict__ p1,
                                             const float* __restrict__ p23) {
    int n = (blockIdx.x * 256 + threadIdx.x) * 4;
    float4 a = *(float4*)&u[n];
    float4 x = *(const float4*)&p1[n];
    float4 y = *(const float4*)&p23[n];
    float4 z = *(const float4*)&p23[PART_FLOATS + n];
    a.x += x.x + y.x + z.x;
    a.y += x.y + y.y + z.y;
    a.z += x.z + y.z + z.z;
    a.w += x.w + y.w + z.w;
    *(float4*)&u[n] = a;
}

// ---------------- u_hat: u[b,i,p] x W[i,j,p,q] -> uhat bf16 [b][j][i*16+q] ---------------
// R14 (verified): [b][j][i16q] layout; for fixed (j,bb) the block stores 2 KB fully
// contiguous within one j-iteration; route_k reads 512 B contiguous per wave per j.
__global__ __launch_bounds__(256) void uhat_k(const float* __restrict__ u,
                                              const float* __restrict__ W,
                                              unsigned short* __restrict__ uhat) {
    int i0 = blockIdx.x * 64;
    int b0 = blockIdx.y * 8;
    __shared__ float ul[8 * 64 * 9];
    __shared__ float wl[64 * 129];
    int tid = threadIdx.x;

    for (int t = tid; t < 4096; t += 256) {
        int bb = t >> 9, r = t & 511;
        ul[bb * 576 + (r >> 3) * 9 + (r & 7)] = u[(b0 + bb) * 9216 + i0 * 8 + r];
    }

    int il = tid & 63, g = tid >> 6;
    for (int j = 0; j < 10; j++) {
        __syncthreads();
        for (int t = tid; t < 2048; t += 256) {
            int li = t >> 5, off = (t & 31) * 4;
            float4 v = *(const float4*)&W[(i0 + li) * 1280 + j * 128 + off];
            float* d = &wl[li * 129 + off];
            d[0] = v.x; d[1] = v.y; d[2] = v.z; d[3] = v.w;
        }
        __syncthreads();
#pragma unroll 1
        for (int bb = 0; bb < 8; bb++) {
            float ur[8];
#pragma unroll
            for (int p = 0; p < 8; p++) ur[p] = ul[bb * 576 + il * 9 + p];
            float a[4];
#pragma unroll
            for (int k = 0; k < 4; k++) {
                int q = g * 4 + k;
                float s = 0.f;
#pragma unroll
                for (int p = 0; p < 8; p++) s += ur[p] * wl[il * 129 + p * 16 + q];
                a[k] = s;
            }
            unsigned int lo = (unsigned int)f2bf(a[0]) | ((unsigned int)f2bf(a[1]) << 16);
            unsigned int hi = (unsigned int)f2bf(a[2]) | ((unsigned int)f2bf(a[3]) << 16);
            uint2 pk; pk.x = lo; pk.y = hi;
            *(uint2*)&uhat[((size_t)(b0 + bb) * 10 + j) * 18432 + (size_t)(i0 + il) * 16 + g * 4] = pk;
        }
    }
}

// ---------------- fused dynamic routing: one block per batch sample ----------------------
// R13 (verified): b_ij in LDS, s/v in LDS, zero global atomics, no inter-kernel drains.
// uhat[b] (360 KB, L2/L3-resident) streamed 3x. R14: [b][j][i16q] layout -> 512 B
// contiguous per wave per j.
__global__ __launch_bounds__(256) void route_k(const unsigned short* __restrict__ uhat,
                                               float* __restrict__ out) {
    int b = blockIdx.x;
    int tid = threadIdx.x;
    int w = tid >> 6, lane = tid & 63;
    int ig = lane >> 2, qh = lane & 3;
    __shared__ float b_sh[1152 * 10];   // 46 KB
    __shared__ float s_red[4 * 160];
    __shared__ float v_sh[160];
    __shared__ float sc_sh[10];
    const unsigned short* ub = uhat + (size_t)b * 184320;

    float v_ln[10][4];   // this lane's v[j*16 + qh*4 + k]

    // reduce sp -> s -> squash -> v_sh -> v_ln  (shared tail for every pass)
    auto finish = [&](float sp[10][4]) {
#pragma unroll
        for (int j = 0; j < 10; j++)
#pragma unroll
            for (int k = 0; k < 4; k++) {
                float t = sp[j][k];
                t += __shfl_xor(t, 4);
                t += __shfl_xor(t, 8);
                t += __shfl_xor(t, 16);
                t += __shfl_xor(t, 32);
                sp[j][k] = t;
            }
        if (ig == 0) {   // lanes 0..3 of each wave hold the wave totals
#pragma unroll
            for (int j = 0; j < 10; j++) {
                f32x4 v4 = {sp[j][0], sp[j][1], sp[j][2], sp[j][3]};
                *(f32x4*)&s_red[w * 160 + j * 16 + qh * 4] = v4;
            }
        }
        __syncthreads();
        if (tid < 160) {
            float s = s_red[tid] + s_red[160 + tid] + s_red[320 + tid] + s_red[480 + tid];
            s_red[tid] = s;
        }
        __syncthreads();
        if (tid < 10) {
            float sq = 0.f;
#pragma unroll
            for (int q = 0; q < 16; q++) { float x = s_red[tid * 16 + q]; sq += x * x; }
            float norm = sqrtf(sq + 1e-8f);
            sc_sh[tid] = (sq / (1.0f + sq)) / norm;
        }
        __syncthreads();
        if (tid < 160) v_sh[tid] = s_red[tid] * sc_sh[tid >> 4];
        __syncthreads();
#pragma unroll
        for (int j = 0; j < 10; j++) {
            f32x4 v4 = *(const f32x4*)&v_sh[j * 16 + qh * 4];
            v_ln[j][0] = v4[0]; v_ln[j][1] = v4[1]; v_ln[j][2] = v4[2]; v_ln[j][3] = v4[3];
        }
        __syncthreads();
    };

    // ---- pass 1: c = 0.1 uniform ----
    {
        float sp[10][4];
#pragma unroll
        for (int j = 0; j < 10; j++)
#pragma unroll
            for (int k = 0; k < 4; k++) sp[j][k] = 0.f;
#pragma unroll 2
        for (int r = 0; r < 18; r++) {
            int i = r * 64 + w * 16 + ig;
            const unsigned short* up = ub + (size_t)i * 16 + qh * 4;
            uint2 uh[10];
#pragma unroll
            for (int j = 0; j < 10; j++) uh[j] = *(const uint2*)(up + (size_t)j * 18432);
#pragma unroll
            for (int j = 0; j < 10; j++) {
                sp[j][0] += 0.1f * bflo(uh[j].x);
                sp[j][1] += 0.1f * bfhi(uh[j].x);
                sp[j][2] += 0.1f * bflo(uh[j].y);
                sp[j][3] += 0.1f * bfhi(uh[j].y);
            }
        }
        finish(sp);
    }

    // ---- passes 2,3: delta = uhat.v, b update, softmax, s-accumulate ----
#pragma unroll 1
    for (int pass = 0; pass < 2; pass++) {
        bool first = (pass == 0);    // pass2: b_prev = 0, write b_sh; pass3: read b_sh
        float sp[10][4];
#pragma unroll
        for (int j = 0; j < 10; j++)
#pragma unroll
            for (int k = 0; k < 4; k++) sp[j][k] = 0.f;
#pragma unroll 2
        for (int r = 0; r < 18; r++) {
            int i = r * 64 + w * 16 + ig;
            const unsigned short* up = ub + (size_t)i * 16 + qh * 4;
            uint2 uh[10];
#pragma unroll
            for (int j = 0; j < 10; j++) uh[j] = *(const uint2*)(up + (size_t)j * 18432);
            float d[10];
#pragma unroll
            for (int j = 0; j < 10; j++) {
                d[j] = bflo(uh[j].x) * v_ln[j][0] + bfhi(uh[j].x) * v_ln[j][1]
                     + bflo(uh[j].y) * v_ln[j][2] + bfhi(uh[j].y) * v_ln[j][3];
            }
#pragma unroll
            for (int j = 0; j < 10; j++) {
                d[j] += __shfl_xor(d[j], 1);
                d[j] += __shfl_xor(d[j], 2);
            }
            float bn[10];
            if (first) {
#pragma unroll
                for (int j = 0; j < 10; j++) bn[j] = d[j];
#pragma unroll
                for (int j = 0; j < 10; j++)
                    if (qh == (j & 3)) b_sh[i * 10 + j] = bn[j];
            } else {
#pragma unroll
                for (int j = 0; j < 10; j++) bn[j] = b_sh[i * 10 + j] + d[j];
            }
            float m = bn[0];
#pragma unroll
            for (int j = 1; j < 10; j++) m = fmaxf(m, bn[j]);
            float e[10], sum = 0.f;
#pragma unroll
            for (int j = 0; j < 10; j++) { e[j] = __expf(bn[j] - m); sum += e[j]; }
            float inv = 1.f / sum;
#pragma unroll
            for (int j = 0; j < 10; j++) {
                float c = e[j] * inv;
                sp[j][0] += c * bflo(uh[j].x);
                sp[j][1] += c * bfhi(uh[j].x);
                sp[j][2] += c * bflo(uh[j].y);
                sp[j][3] += c * bfhi(uh[j].y);
            }
        }
        finish(sp);
    }

    if (tid < 160) out[b * 160 + tid] = v_sh[tid];
}

extern "C" void kernel_launch(void* const* d_in, const int* in_sizes, int n_in,
                              void* d_out, int out_size, void* d_ws, size_t ws_size,
                              hipStream_t stream) {
    const float* input = (const float*)d_in[0];
    const float* c1w = (const float*)d_in[1];
    const float* c1b = (const float*)d_in[2];
    const float* c2w = (const float*)d_in[3];
    const float* c2b = (const float*)d_in[4];
    const float* capW = (const float*)d_in[5];
    float* out = (float*)d_out;

    // ws layout (bytes):
    //   [0)            u fp32 [512][9216]                      18,874,368
    //   [+19529728)    conv2 split-K part1                     18,874,368
    //   [+43122688)    region B: {Wt2 84 planes + h1n + part2,3} then uhat bf16 reuse
    const size_t U_OFF = 0;
    const size_t L_OFF = 19529728;
    const size_t B_OFF = 43122688;
    const size_t WT2_BYTES = (size_t)84 * 65536 * 2;       // 11,010,048
    const size_t H1N_BYTES = 104857600;
    const size_t PART_BYTES = (size_t)PART_FLOATS * 4;     // 18,874,368
    const size_t CONV_BYTES = WT2_BYTES + H1N_BYTES + 2 * PART_BYTES;  // 153.6 MB
    if (ws_size < B_OFF + CONV_BYTES) return;

    char* wsb = (char*)d_ws;
    float* u_buf = (float*)(wsb + U_OFF);
    float* part1  = (float*)(wsb + L_OFF);
    unsigned short* Wt2 = (unsigned short*)(wsb + B_OFF);
    unsigned short* h1n = (unsigned short*)(wsb + B_OFF + WT2_BYTES);
    float* part23 = (float*)(wsb + B_OFF + WT2_BYTES + H1N_BYTES);
    unsigned short* uhatb = (unsigned short*)(wsb + B_OFF);

    size_t availB = ws_size - B_OFF;
    int Cr = 0;
    const int cands[7] = {512, 256, 128, 64, 32, 16, 8};
    for (int k = 0; k < 7; k++) {
        if ((size_t)cands[k] * 368640 <= availB) { Cr = cands[k]; break; }
    }
    if (Cr == 0) return;

    wt2_k<<<256, 256, 0, stream>>>(c2w, Wt2);
    conv1_k<<<512 * 16, 320, 0, stream>>>(input, c1w, c1b, h1n);
    conv2_k<<<dim3(144, 2, 4), 256, 0, stream>>>(h1n, Wt2, c2b, u_buf, part1, part23);
    add_k<<<4608, 256, 0, stream>>>(u_buf, part1, part23);

    for (int b0 = 0; b0 < 512; b0 += Cr) {
        uhat_k<<<dim3(18, Cr / 8), 256, 0, stream>>>(u_buf + (size_t)b0 * 9216, capW,
                                                     uhatb + (size_t)b0 * 184320);
        route_k<<<Cr, 256, 0, stream>>>(uhatb + (size_t)b0 * 184320, out + (size_t)b0 * 160);
    }
}